// Round 9
// baseline (87.811 us; speedup 1.0000x reference)
//
#include <hip/hip_runtime.h>

typedef float f2 __attribute__((ext_vector_type(2)));

static constexpr int B = 128;
static constexpr int G = 64;
static constexpr int P = 8732;
static constexpr float EPS = 1e-5f;
static constexpr float IOU_THR = 0.5f;

__device__ __forceinline__ void encode_store(
    float* out_loc, float* out_lab, int b, int p,
    float4 gb, float4 pr, int lab)
{
    float cx = (gb.x + gb.z) * 0.5f;
    float cy = (gb.y + gb.w) * 0.5f;
    float w  = gb.z - gb.x;
    float h  = gb.w - gb.y;
    float4 loc;
    loc.x = (cx - pr.x) / (pr.z * 0.1f);
    loc.y = (cy - pr.y) / (pr.w * 0.1f);
    loc.z = logf(w / pr.z) / 0.2f;
    loc.w = logf(h / pr.w) / 0.2f;
    *(float4*)(out_loc + (size_t)(b * P + p) * 4) = loc;
    out_lab[(size_t)b * P + p] = (float)lab;
}

// Prep: FIELD-MAJOR gt_ext[b][f][64], f = {x1,y1,x2,y2,area}, so the hot loop
// can s_load_dwordx2 a g-PAIR of each field into an SGPR pair that feeds
// VOP3P (v_pk_*_f32) directly. Also zeroes packed (atomicMax is monotone;
// the 0xAA poison would otherwise win forever).
__global__ __launch_bounds__(64) void k_prep(
    const float* __restrict__ gt_boxes,
    float* __restrict__ gt_ext,
    unsigned long long* __restrict__ packed)
{
    const int b = blockIdx.x;
    const int g = threadIdx.x;
    float4 gb = *(const float4*)(gt_boxes + (size_t)(b * G + g) * 4);
    float ga = __fmul_rn(fmaxf(__fsub_rn(gb.z, gb.x), 0.0f),
                         fmaxf(__fsub_rn(gb.w, gb.y), 0.0f));
    float* ge = gt_ext + (size_t)b * 5 * G;
    ge[0 * G + g] = gb.x;
    ge[1 * G + g] = gb.y;
    ge[2 * G + g] = gb.z;
    ge[3 * G + g] = gb.w;
    ge[4 * G + g] = ga;
    packed[b * G + g] = 0ull;
}

// Fused single pass over all B*G*P IoUs, g processed in PAIRS: gt operands are
// wave-uniform SGPR pairs (s_load_dwordx2), prior operands are hoisted VGPR
// splats, arithmetic lowers to packed VOP3P where available. Every per-element
// rounding is bit-identical to the numpy chain:
//   lt=max, rb=min, hw=max(rb-lt,0), ov=hw0*hw1, den=((ga+pa)-ov)+eps, ov/den
// with division = correctly-rounded 6-op Markstein (valid: den in [1e-5,2.5]
// normal; ov==0 -> +0 exactly). Contraction hazards blocked: t2 uses
// fma(ov,-1,t1) (product exact => bits == fsub); prior prologue uses __f*_rn.
__global__ __launch_bounds__(256, 8) void k_fused(
    const float* __restrict__ gt_boxes,       // [B,G,4] corner (epilogue gather)
    const int*   __restrict__ gt_labels,      // [B,G]
    const float* __restrict__ priors,         // [P,4] center
    const float* __restrict__ gt_ext,         // [B,5,G] field-major
    unsigned long long* __restrict__ packed,  // [B,G]
    float* __restrict__ out_loc,              // [B,P,4]
    float* __restrict__ out_lab)              // [B,P]
{
    __shared__ float4 s_gt[G];                 // final divergent gather only
    __shared__ unsigned long long s_red[G];
    __shared__ int   s_lab[G];
    __shared__ float s_iou[256][17];           // odd stride: 2-way alias = free

    const int b = blockIdx.y;
    const int t = threadIdx.x;
    const int pbase = blockIdx.x * 256;
    const int p = pbase + t;
    const bool valid = p < P;

    const float* __restrict__ ge = gt_ext + (size_t)b * 5 * G;  // uniform base

    if (t < G) {
        s_gt[t]  = *(const float4*)(gt_boxes + (size_t)(b * G + t) * 4);
        s_lab[t] = gt_labels[b * G + t];
        s_red[t] = 0ull;
    }
    __syncthreads();

    // Invalid lanes: degenerate zero prior -> iou == +0.0f exactly for all g;
    // they occupy the largest row indices of the tail block, so ascending
    // strict-> scans and the ~p key packing lose every tie to valid rows.
    float4 pr = make_float4(0.f, 0.f, 0.f, 0.f);
    if (valid) pr = *(const float4*)(priors + (size_t)p * 4);
    float hw = __fmul_rn(pr.z, 0.5f), hh = __fmul_rn(pr.w, 0.5f);
    float px1 = __fsub_rn(pr.x, hw), py1 = __fsub_rn(pr.y, hh);
    float px2 = __fadd_rn(pr.x, hw), py2 = __fadd_rn(pr.y, hh);
    float pa  = __fmul_rn(fmaxf(__fsub_rn(px2, px1), 0.0f),
                          fmaxf(__fsub_rn(py2, py1), 0.0f));

    // Hoisted VGPR-pair splats for the packed ops.
    const f2 vpx1 = {px1, px1}, vpy1 = {py1, py1};
    const f2 vpx2 = {px2, px2}, vpy2 = {py2, py2};
    const f2 vpa  = {pa, pa},   veps = {EPS, EPS};
    const f2 vone = {1.0f, 1.0f}, vnegone = {-1.0f, -1.0f};
    const f2 vzero = {0.0f, 0.0f};

    float bestIou = -1.0f;
    int   bestG   = 0;

    for (int q4 = 0; q4 < 4; ++q4) {
        const int gbase = q4 * 16;
        // phase1: 16 ious as 8 g-pairs; gt fields arrive as SGPR pairs.
#pragma unroll
        for (int k2 = 0; k2 < 8; ++k2) {
            const int g0 = gbase + 2 * k2;
            f2 gx1 = *(const f2*)(ge + 0 * G + g0);   // s_load_dwordx2
            f2 gy1 = *(const f2*)(ge + 1 * G + g0);
            f2 gx2 = *(const f2*)(ge + 2 * G + g0);
            f2 gy2 = *(const f2*)(ge + 3 * G + g0);
            f2 ga  = *(const f2*)(ge + 4 * G + g0);

            f2 ltx = __builtin_elementwise_max(gx1, vpx1);  // 2x v_max_f32
            f2 lty = __builtin_elementwise_max(gy1, vpy1);
            f2 rbx = __builtin_elementwise_min(gx2, vpx2);
            f2 rby = __builtin_elementwise_min(gy2, vpy2);
            f2 dx  = rbx - ltx;                     // pk_add(neg)
            f2 dy  = rby - lty;
            f2 ow  = __builtin_elementwise_max(dx, vzero);
            f2 oh  = __builtin_elementwise_max(dy, vzero);
            f2 ov  = ow * oh;                       // pk_mul
            f2 t1  = ga + vpa;                      // pk_add (1 SGPR operand)
            f2 t2  = __builtin_elementwise_fma(ov, vnegone, t1);  // == t1-ov
            f2 den = t2 + veps;                     // pk_add
            f2 r0  = {__builtin_amdgcn_rcpf(den.x), __builtin_amdgcn_rcpf(den.y)};
            f2 e   = __builtin_elementwise_fma(-den, r0, vone);
            f2 r1  = __builtin_elementwise_fma(e, r0, r0);
            f2 q0  = ov * r1;                       // pk_mul
            f2 rem = __builtin_elementwise_fma(-den, q0, ov);
            f2 qq  = __builtin_elementwise_fma(rem, r1, q0);

            s_iou[t][2 * k2]     = qq.x;            // merges to ds_write2_b32
            s_iou[t][2 * k2 + 1] = qq.y;

            // Pair-combine argmax, equivalent to sequential first-g scan:
            // tie (qq.y == qq.x) -> keep g0; strict > vs running best.
            int   selg = (qq.y > qq.x) ? g0 + 1 : g0;
            float v    = fmaxf(qq.x, qq.y);
            if (v > bestIou) { bestIou = v; bestG = selg; }
        }
        __syncthreads();

        // phase2: per-g argmax over this block's 256 p's.
        // 16 threads per column (t&15 = col, t>>4 = row-group of 16); ascending
        // rows + strict > = smallest p wins ties; cross-thread/-block merge via
        // packed (iou<<32)|(~p) atomicMax (order-independent, deterministic).
        {
            const int c   = t & 15;
            const int r0s = (t >> 4) * 16;
            float bv = -0.5f;
            int   br = 0;
#pragma unroll
            for (int j = 0; j < 16; ++j) {
                float v = s_iou[r0s + j][c];
                if (v > bv) { bv = v; br = r0s + j; }
            }
            unsigned long long key =
                ((unsigned long long)__float_as_uint(bv) << 32) |
                (unsigned long long)(0xFFFFFFFFu - (unsigned)(pbase + br));
            atomicMax(&s_red[gbase + c], key);
        }
        __syncthreads();
    }

    if (t < G) {
        atomicMax(&packed[(size_t)b * G + t], s_red[t]);
    }

    if (valid) {
        int lab = (bestIou < IOU_THR) ? 0 : s_lab[bestG];
        encode_store(out_loc, out_lab, b, p, s_gt[bestG], pr, lab);
    }
}

// Force-assign fixup: each gt overwrites its best prior; duplicate p resolved
// last-g-wins (matches jnp .at[].set scatter order).
__global__ __launch_bounds__(64) void k_fixup(
    const float* __restrict__ gt_boxes,
    const int*   __restrict__ gt_labels,
    const float* __restrict__ priors,
    const unsigned long long* __restrict__ packed,
    float* __restrict__ out_loc,
    float* __restrict__ out_lab)
{
    __shared__ int s_p[G];
    const int b = blockIdx.x;
    const int g = threadIdx.x;

    unsigned long long key = packed[(size_t)b * G + g];
    int p = (int)(0xFFFFFFFFu - (unsigned)(key & 0xFFFFFFFFull));
    s_p[g] = p;
    __syncthreads();

    bool win = true;
    for (int g2 = g + 1; g2 < G; ++g2)
        if (s_p[g2] == p) { win = false; break; }

    if (win) {
        float4 gb = *(const float4*)(gt_boxes + (size_t)(b * G + g) * 4);
        float4 pr = *(const float4*)(priors + (size_t)p * 4);
        int lab = gt_labels[b * G + g];   // forced: iou=2.0 >= thr, label kept
        encode_store(out_loc, out_lab, b, p, gb, pr, lab);
    }
}

extern "C" void kernel_launch(void* const* d_in, const int* in_sizes, int n_in,
                              void* d_out, int out_size, void* d_ws, size_t ws_size,
                              hipStream_t stream)
{
    const float* gt_boxes  = (const float*)d_in[0];
    const int*   gt_labels = (const int*)d_in[1];
    const float* priors    = (const float*)d_in[2];

    float* out_loc = (float*)d_out;                   // B*P*4 floats
    float* out_lab = out_loc + (size_t)B * P * 4;     // B*P floats

    // ws layout: packed [B*G] u64 (64 KB) | gt_ext [B,5,G] f32 (160 KB)
    unsigned long long* packed = (unsigned long long*)d_ws;
    float* gt_ext = (float*)((char*)d_ws + (size_t)B * G * sizeof(unsigned long long));

    k_prep<<<dim3(B), 64, 0, stream>>>(gt_boxes, gt_ext, packed);

    k_fused<<<dim3((P + 255) / 256, B), 256, 0, stream>>>(
        gt_boxes, gt_labels, priors, gt_ext, packed, out_loc, out_lab);

    k_fixup<<<dim3(B), 64, 0, stream>>>(
        gt_boxes, gt_labels, priors, packed, out_loc, out_lab);
}

// Round 11
// 68.819 us; speedup vs baseline: 1.2760x; 1.2760x over previous
//
#include <hip/hip_runtime.h>

static constexpr int B = 128;
static constexpr int G = 64;
static constexpr int P = 8732;
static constexpr int NXB = (P + 255) / 256;   // 35 x-blocks
static constexpr float EPS = 1e-5f;
static constexpr float IOU_THR = 0.5f;

// Correctly-rounded f32 division for guaranteed-normal operands (Markstein,
// 6 ops, no VCC serialization). Bit-identical to IEEE div for our ranges:
// d in [1e-5, 2.5] (normal), x == +-0 or normal in [~1e-20, 2]; x=0 -> +0.
// r1 is within 0.5 ulp of 1/d after one NR step from the <=1-ulp v_rcp_f32,
// so the final fma-corrected quotient is correctly rounded.
__device__ __forceinline__ float div_rn_normal(float x, float d)
{
    float r0  = __builtin_amdgcn_rcpf(d);
    float e   = __fmaf_rn(-d, r0, 1.0f);
    float r1  = __fmaf_rn(e, r0, r0);
    float q0  = __fmul_rn(x, r1);
    float rem = __fmaf_rn(-d, q0, x);
    return __fmaf_rn(rem, r1, q0);
}

// Bitwise-numpy-identical IoU chain:
//   lt=max, rb=min, hw=max(rb-lt,0), ov=hw0*hw1, den=((ga+pa)-ov)+eps, ov/den
__device__ __forceinline__ float iou_exact(
    float gx1, float gy1, float gx2, float gy2, float ga,
    float px1, float py1, float px2, float py2, float pa)
{
    float ltx = fmaxf(gx1, px1), lty = fmaxf(gy1, py1);
    float rbx = fminf(gx2, px2), rby = fminf(gy2, py2);
    float ow  = fmaxf(__fsub_rn(rbx, ltx), 0.0f);
    float oh  = fmaxf(__fsub_rn(rby, lty), 0.0f);
    float ov  = __fmul_rn(ow, oh);
    float den = __fadd_rn(__fsub_rn(__fadd_rn(ga, pa), ov), EPS);
    return div_rn_normal(ov, den);
}

__device__ __forceinline__ void encode_store(
    float* out_loc, float* out_lab, int b, int p,
    float4 gb, float4 pr, int lab)
{
    float cx = (gb.x + gb.z) * 0.5f;
    float cy = (gb.y + gb.w) * 0.5f;
    float w  = gb.z - gb.x;
    float h  = gb.w - gb.y;
    float4 loc;
    loc.x = (cx - pr.x) / (pr.z * 0.1f);
    loc.y = (cy - pr.y) / (pr.w * 0.1f);
    loc.z = logf(w / pr.z) / 0.2f;
    loc.w = logf(h / pr.w) / 0.2f;
    *(float4*)(out_loc + (size_t)(b * P + p) * 4) = loc;
    out_lab[(size_t)b * P + p] = (float)lab;
}

// Fused single pass over all B*G*P IoUs. Per-block LDS staging of gt
// (broadcast reads are conflict-free), Markstein division, and per-block
// partial argmax keys written with PLAIN stores (no global atomics -> no
// zeroing kernel; ws is overwritten deterministically every call).
__global__ __launch_bounds__(256, 8) void k_fused(
    const float* __restrict__ gt_boxes,       // [B,G,4] corner
    const int*   __restrict__ gt_labels,      // [B,G]
    const float* __restrict__ priors,         // [P,4] center
    unsigned long long* __restrict__ part,    // [B,G,NXB] partial keys
    float* __restrict__ out_loc,              // [B,P,4]
    float* __restrict__ out_lab)              // [B,P]
{
    __shared__ float4 s_gt[G];
    __shared__ unsigned long long s_red[G];
    __shared__ float s_ga[G];
    __shared__ int   s_lab[G];
    __shared__ float s_iou[256][17];          // odd stride: 2-way alias = free

    const int b = blockIdx.y;
    const int t = threadIdx.x;
    const int pbase = blockIdx.x * 256;
    const int p = pbase + t;
    const bool valid = p < P;

    if (t < G) {
        float4 gb = *(const float4*)(gt_boxes + (size_t)(b * G + t) * 4);
        s_gt[t]  = gb;
        s_ga[t]  = __fmul_rn(fmaxf(__fsub_rn(gb.z, gb.x), 0.0f),
                             fmaxf(__fsub_rn(gb.w, gb.y), 0.0f));
        s_lab[t] = gt_labels[b * G + t];
        s_red[t] = 0ull;
    }
    __syncthreads();

    // Invalid lanes: degenerate zero prior -> iou == +0.0f exactly for all g;
    // they occupy the largest row indices of the tail block, so ascending
    // strict-> scans and the ~p key packing lose every tie to valid rows.
    float4 pr = make_float4(0.f, 0.f, 0.f, 0.f);
    if (valid) pr = *(const float4*)(priors + (size_t)p * 4);
    float hw = __fmul_rn(pr.z, 0.5f), hh = __fmul_rn(pr.w, 0.5f);
    float px1 = __fsub_rn(pr.x, hw), py1 = __fsub_rn(pr.y, hh);
    float px2 = __fadd_rn(pr.x, hw), py2 = __fadd_rn(pr.y, hh);
    float pa  = __fmul_rn(fmaxf(__fsub_rn(px2, px1), 0.0f),
                          fmaxf(__fsub_rn(py2, py1), 0.0f));

    float bestIou = -1.0f;
    int   bestG   = 0;

    for (int q = 0; q < 4; ++q) {
        const int gbase = q * 16;
        // phase1: 16 ious; gt via conflict-free LDS broadcast reads.
#pragma unroll
        for (int gi = 0; gi < 16; ++gi) {
            const int g = gbase + gi;
            float4 gb = s_gt[g];
            float iou = iou_exact(gb.x, gb.y, gb.z, gb.w, s_ga[g],
                                  px1, py1, px2, py2, pa);
            s_iou[t][gi] = iou;
            if (iou > bestIou) { bestIou = iou; bestG = g; }  // first-g ties
        }
        __syncthreads();

        // phase2: per-g argmax over this block's 256 p's.
        // 16 threads per column (t&15 = col, t>>4 = row-group of 16); ascending
        // rows + strict > = smallest p wins ties; merge via LDS atomicMax of
        // packed (iou<<32)|(~p) keys (order-independent, deterministic).
        {
            const int c   = t & 15;
            const int r0s = (t >> 4) * 16;
            float bv = -0.5f;
            int   br = 0;
#pragma unroll
            for (int j = 0; j < 16; ++j) {
                float v = s_iou[r0s + j][c];
                if (v > bv) { bv = v; br = r0s + j; }
            }
            unsigned long long key =
                ((unsigned long long)__float_as_uint(bv) << 32) |
                (unsigned long long)(0xFFFFFFFFu - (unsigned)(pbase + br));
            atomicMax(&s_red[gbase + c], key);
        }
        __syncthreads();
    }

    // Plain partial-key store: no global atomics, no pre-zeroing needed.
    if (t < G) {
        part[((size_t)b * G + t) * NXB + blockIdx.x] = s_red[t];
    }

    if (valid) {
        int lab = (bestIou < IOU_THR) ? 0 : s_lab[bestG];
        encode_store(out_loc, out_lab, b, p, s_gt[bestG], pr, lab);
    }
}

// Reduce the 35 per-block partials per (b,g), then force-assign each gt its
// best prior; duplicate p resolved last-g-wins (matches jnp .at[].set order).
__global__ __launch_bounds__(64) void k_fixup(
    const float* __restrict__ gt_boxes,
    const int*   __restrict__ gt_labels,
    const float* __restrict__ priors,
    const unsigned long long* __restrict__ part,   // [B,G,NXB]
    float* __restrict__ out_loc,
    float* __restrict__ out_lab)
{
    __shared__ int s_p[G];
    const int b = blockIdx.x;
    const int g = threadIdx.x;

    const unsigned long long* row = part + ((size_t)b * G + g) * NXB;
    unsigned long long key = 0ull;
#pragma unroll 5
    for (int xb = 0; xb < NXB; ++xb) {
        unsigned long long k = row[xb];
        key = k > key ? k : key;
    }
    int p = (int)(0xFFFFFFFFu - (unsigned)(key & 0xFFFFFFFFull));
    s_p[g] = p;
    __syncthreads();

    bool win = true;
    for (int g2 = g + 1; g2 < G; ++g2)
        if (s_p[g2] == p) { win = false; break; }

    if (win) {
        float4 gb = *(const float4*)(gt_boxes + (size_t)(b * G + g) * 4);
        float4 pr = *(const float4*)(priors + (size_t)p * 4);
        int lab = gt_labels[b * G + g];   // forced: iou=2.0 >= thr, label kept
        encode_store(out_loc, out_lab, b, p, gb, pr, lab);
    }
}

extern "C" void kernel_launch(void* const* d_in, const int* in_sizes, int n_in,
                              void* d_out, int out_size, void* d_ws, size_t ws_size,
                              hipStream_t stream)
{
    const float* gt_boxes  = (const float*)d_in[0];
    const int*   gt_labels = (const int*)d_in[1];
    const float* priors    = (const float*)d_in[2];

    float* out_loc = (float*)d_out;                   // B*P*4 floats
    float* out_lab = out_loc + (size_t)B * P * 4;     // B*P floats

    // ws: part [B,G,NXB] u64 = 2.29 MB, fully overwritten every call.
    unsigned long long* part = (unsigned long long*)d_ws;

    k_fused<<<dim3(NXB, B), 256, 0, stream>>>(
        gt_boxes, gt_labels, priors, part, out_loc, out_lab);

    k_fixup<<<dim3(B), 64, 0, stream>>>(
        gt_boxes, gt_labels, priors, part, out_loc, out_lab);
}